// Round 11
// baseline (128.366 us; speedup 1.0000x reference)
//
#include <hip/hip_runtime.h>
#include <cstdint>
#include <cstddef>

// MMD loss, N=8192 (b=4096), D=512.
//   bw closed form: sum(L2) = 2n*S - 2*||colsum||^2
//   R11: A-IN-REGISTERS / B-THROUGH-LDS restructure. Block = 256x256 outputs
//        (528 blocks, uniform work). Each wave holds its 64-row x K=512 A
//        panel in 128 VGPRs (af[4][8], loaded once). B staged per 32-col
//        btile (16KB) into dbuf LDS via global_load_lds; 4 waves share it ->
//        zero dup. L2 traffic 532 -> 135 MB. Triangle handled by per-element
//        weight {0,1,2} (uniform fast path for interior btiles); sign uniform
//        per block. Fixes the R6-R10 plateau (128x128 tiles re-streamed A+B
//        from L2 at ~13TB/s pure-L2 ceiling = ~40us floor).
//   R6: fragment-major int8 layout: chunk (rb,c) = 16 rows x 16B as one
//       contiguous 256B block; fragment load = one 1KB wave transaction.
//   R4: INT8 MFMA 16x16x64 (scale 1/16, exact int32 acc).
//   Epilogue: sum_k exp(-L2/(bw*2^k)) = e+e^2+e^4+e^8+e^16, e=exp2(-L2*log2e/(16bw))
//   R2: no single-address atomics (were 107us of serialization).

#define D_DIM 512
#define B_ROWS 4096
#define N_ROWS 8192
#define NSTRIP 32        // 256-row strips
#define NBLK_MMD 528     // sum_{si=0}^{31} (32 - si)

typedef __attribute__((ext_vector_type(4))) int i32x4;

#define AS1(p) ((const __attribute__((address_space(1))) void*)(p))
#define AS3(p) ((__attribute__((address_space(3))) void*)(p))

__device__ inline float waveReduce(float v) {
    #pragma unroll
    for (int off = 32; off > 0; off >>= 1) v += __shfl_down(v, off, 64);
    return v;
}

__device__ inline int q8(float x) {
    int v = (int)rintf(x * 16.f);             // RNE; s = 1/16
    v = v > 127 ? 127 : v;
    v = v < -127 ? -127 : v;
    return v & 255;
}

// Fragment-major address: row r, 16B-chunk c (0..31):
//   rb = r>>4, w = r&15;  byte addr = ((rb*32 + c) << 8) + w*16
//                                   = (rb<<13) + (c<<8) + w*16

// ---- K1: per-row sq norms (fp32, exact) + fp32->int8 quantize (frag-major) ----
__global__ __launch_bounds__(256) void k_rowstats(const float* __restrict__ src,
                                                  const float* __restrict__ tgt,
                                                  unsigned char* __restrict__ Tp,
                                                  float* __restrict__ sq) {
    int wave = threadIdx.x >> 6;
    int lane = threadIdx.x & 63;
    int row  = blockIdx.x * 4 + wave;
    const float* base = (row < B_ROWS) ? (src + (size_t)row * D_DIM)
                                       : (tgt + (size_t)(row - B_ROWS) * D_DIM);
    float4 a = ((const float4*)base)[lane * 2];
    float4 b = ((const float4*)base)[lane * 2 + 1];
    uint2 o;   // bytes [8*lane, 8*lane+8) of the quantized row
    o.x = (unsigned)(q8(a.x) | (q8(a.y) << 8) | (q8(a.z) << 16) | (q8(a.w) << 24));
    o.y = (unsigned)(q8(b.x) | (q8(b.y) << 8) | (q8(b.z) << 16) | (q8(b.w) << 24));
    int rb = row >> 4, w = row & 15;
    int c  = lane >> 1, h = lane & 1;
    *(uint2*)(Tp + (((size_t)(rb * 32 + c)) << 8) + w * 16 + h * 8) = o;
    float s = a.x*a.x + a.y*a.y + a.z*a.z + a.w*a.w
            + b.x*b.x + b.y*b.y + b.z*b.z + b.w*b.w;
    s = waveReduce(s);
    if (lane == 0) sq[row] = s;
}

// ---- K2: exact int8 column-sum partials from frag-major layout ----
__global__ __launch_bounds__(256) void k_colsum(const unsigned int* __restrict__ Tu,
                                                int* __restrict__ partial) {
    int t   = threadIdx.x;
    int u   = t & 127;
    int c   = u >> 2, q = u & 3;
    int sub = t >> 7;              // w in [sub*8, sub*8+8)
    int a0 = 0, a1 = 0, a2 = 0, a3 = 0;
    #pragma unroll 2
    for (int j = 0; j < 8; ++j) {
        int rb = blockIdx.x * 8 + j;
        #pragma unroll
        for (int wv = 0; wv < 8; ++wv) {
            int w = sub * 8 + wv;
            unsigned int v = Tu[(size_t)(rb * 32 + c) * 64 + w * 4 + q];
            a0 += (int)(signed char)(v);
            a1 += (int)(signed char)(v >> 8);
            a2 += (int)(signed char)(v >> 16);
            a3 += (int)(signed char)(v >> 24);
        }
    }
    int basep = (blockIdx.x * 2 + sub) * 512 + u * 4;
    partial[basep + 0] = a0;
    partial[basep + 1] = a1;
    partial[basep + 2] = a2;
    partial[basep + 3] = a3;
}

// ---- K3: finalize bandwidth -> c16 = -log2(e)/(16*bw) ----
__global__ __launch_bounds__(512) void k_bw(const int* __restrict__ partial,
                                            const float* __restrict__ sq,
                                            float* __restrict__ c16out) {
    int t = threadIdx.x;
    int csum = 0;
    #pragma unroll 8
    for (int i = 0; i < 128; ++i) csum += partial[i * 512 + t];
    float cs = (float)csum * 0.0625f;          // * s (1/16)
    float p = cs * cs;
    float ssq = 0.f;
    #pragma unroll
    for (int i = 0; i < 16; ++i) ssq += sq[t + i * 512];
    __shared__ float r8[8], q8s[8];
    float wp = waveReduce(p);
    float wq = waveReduce(ssq);
    if ((t & 63) == 0) { r8[t >> 6] = wp; q8s[t >> 6] = wq; }
    __syncthreads();
    if (t == 0) {
        double P = 0.0, Q = 0.0;
        #pragma unroll
        for (int i = 0; i < 8; ++i) { P += r8[i]; Q += q8s[i]; }
        double n = (double)N_ROWS;
        double sumL2 = 2.0 * n * Q - 2.0 * P;
        double bw = sumL2 / (n * n - n) / 4.0;   // / KERNEL_MUL^(NUM/2)
        c16out[0] = (float)(-1.4426950408889634 / (16.0 * bw));
    }
}

// ---- K4: A-in-registers, B-through-LDS int8 Gram + fused MMD epilogue ----
__global__ __launch_bounds__(256) void k_mmd(const unsigned char* __restrict__ Tp,
                                             const float* __restrict__ sq,
                                             const float* __restrict__ c16in,
                                             float* __restrict__ blockpart) {
    // decode (si, cj): strip si (256 rows), col chunk cj (256 cols), cj >= si
    int rem = blockIdx.x, si = 0;
    while (rem >= NSTRIP - si) { rem -= NSTRIP - si; si++; }
    int cj = si + rem;

    int tid  = threadIdx.x;
    int wave = tid >> 6;
    int lane = tid & 63;
    int l15  = lane & 15;
    int quad = lane >> 4;

    __shared__ unsigned char Bs[2][16384];   // dbuf: 32-col B tile, frag-major
    __shared__ float red[4];

    float c16 = c16in[0];                    // -log2e/(16 bw)
    float cgq = -2.f * c16 * (1.f / 256.f);  // fold s^2 = 1/256

    int R0 = si * 256 + wave * 64;           // this wave's A rows [R0, R0+64)

    // A panel into registers: af[mi][kk] = frag of rows [R0+16mi,+16), K-chunk kk*4+quad
    i32x4 af[4][8];
    #pragma unroll
    for (int mi = 0; mi < 4; ++mi) {
        const unsigned char* Ab = Tp + ((size_t)((R0 >> 4) + mi) << 13)
                                     + quad * 256 + l15 * 16;
        #pragma unroll
        for (int kk = 0; kk < 8; ++kk)
            af[mi][kk] = *(const i32x4*)(Ab + kk * 1024);
    }

    float trow16[16];
    #pragma unroll
    for (int mi = 0; mi < 4; ++mi)
        #pragma unroll
        for (int rr = 0; rr < 4; ++rr)
            trow16[mi * 4 + rr] = sq[R0 + mi * 16 + quad * 4 + rr] * c16;

    // prologue: stage btile 0 (16 KB contiguous frag-major: row-blocks 16cj, 16cj+1)
    {
        const unsigned char* Bg = Tp + ((size_t)(cj * 16) << 13);
        #pragma unroll
        for (int i = 0; i < 4; ++i)
            __builtin_amdgcn_global_load_lds(AS1(Bg + i * 4096 + tid * 16),
                                             AS3(&Bs[0][i * 4096 + tid * 16]), 16, 0, 0);
    }
    __syncthreads();

    float bsum = 0.f;
    #pragma unroll 1
    for (int bt = 0; bt < 8; ++bt) {
        int cur = bt & 1;
        if (bt < 7) {   // stage next btile into the other buffer
            const unsigned char* Bg = Tp + ((size_t)(cj * 16 + (bt + 1) * 2) << 13);
            #pragma unroll
            for (int i = 0; i < 4; ++i)
                __builtin_amdgcn_global_load_lds(AS1(Bg + i * 4096 + tid * 16),
                                                 AS3(&Bs[1 - cur][i * 4096 + tid * 16]), 16, 0, 0);
        }

        int C0 = cj * 256 + bt * 32;         // this btile's cols [C0, C0+32)
        if (C0 + 31 >= R0) {                 // wave has work (upper triangle)
            i32x4 acc[4][2];
            #pragma unroll
            for (int mi = 0; mi < 4; ++mi) {
                acc[mi][0] = (i32x4){0, 0, 0, 0};
                acc[mi][1] = (i32x4){0, 0, 0, 0};
            }
            #pragma unroll
            for (int kk = 0; kk < 8; ++kk) {
                int co = ((kk * 4 + quad) << 8) + l15 * 16;
                i32x4 bf0 = *(const i32x4*)(&Bs[cur][co]);
                i32x4 bf1 = *(const i32x4*)(&Bs[cur][8192 + co]);
                #pragma unroll
                for (int mi = 0; mi < 4; ++mi) {
                    acc[mi][0] = __builtin_amdgcn_mfma_i32_16x16x64_i8(
                        af[mi][kk], bf0, acc[mi][0], 0, 0, 0);
                    acc[mi][1] = __builtin_amdgcn_mfma_i32_16x16x64_i8(
                        af[mi][kk], bf1, acc[mi][1], 0, 0, 0);
                }
            }

            float tcol0 = sq[C0 + l15] * c16;
            float tcol1 = sq[C0 + 16 + l15] * c16;
            bool interior = (C0 >= R0 + 64);   // wave-uniform
            float psum = 0.f;
            if (interior) {
                #pragma unroll
                for (int mi = 0; mi < 4; ++mi)
                    #pragma unroll
                    for (int ni = 0; ni < 2; ++ni) {
                        float tcol = ni ? tcol1 : tcol0;
                        #pragma unroll
                        for (int rr = 0; rr < 4; ++rr) {
                            float g   = (float)acc[mi][ni][rr];   // exact
                            float t16 = __builtin_fmaf(g, cgq, trow16[mi * 4 + rr]) + tcol;
                            float e1  = __builtin_amdgcn_exp2f(t16);
                            float e2  = e1 * e1;
                            float e4  = e2 * e2;
                            float e8  = e4 * e4;
                            float e16 = e8 * e8;
                            psum += ((e1 + e2) + (e4 + e8)) + e16;
                        }
                    }
                bsum += 2.f * psum;
            } else {   // straddles the diagonal: per-element weight {0,1,2}
                #pragma unroll
                for (int mi = 0; mi < 4; ++mi)
                    #pragma unroll
                    for (int ni = 0; ni < 2; ++ni) {
                        float tcol = ni ? tcol1 : tcol0;
                        int cl = C0 + ni * 16 + l15;
                        #pragma unroll
                        for (int rr = 0; rr < 4; ++rr) {
                            int rl = R0 + mi * 16 + quad * 4 + rr;
                            float g   = (float)acc[mi][ni][rr];
                            float t16 = __builtin_fmaf(g, cgq, trow16[mi * 4 + rr]) + tcol;
                            float e1  = __builtin_amdgcn_exp2f(t16);
                            float e2  = e1 * e1;
                            float e4  = e2 * e2;
                            float e8  = e4 * e4;
                            float e16 = e8 * e8;
                            float ks5 = ((e1 + e2) + (e4 + e8)) + e16;
                            float wgt = (cl > rl) ? 2.f : ((cl == rl) ? 1.f : 0.f);
                            psum += wgt * ks5;
                        }
                    }
                bsum += psum;
            }
        }
        __syncthreads();   // buffer rotate safety + drains this bt's staging
    }

    float sgn = ((si < 16) == (cj < 16)) ? 1.f : -1.f;
    float w = waveReduce(bsum);
    if (lane == 0) red[wave] = w;
    __syncthreads();
    if (tid == 0)
        blockpart[blockIdx.x] = (red[0] + red[1] + red[2] + red[3]) * sgn;
}

// ---- K5: reduce block partials -> final scalar ----
__global__ __launch_bounds__(256) void k_final(const float* __restrict__ bp,
                                               float* __restrict__ out) {
    int t = threadIdx.x;
    float s = 0.f;
    for (int i = t; i < NBLK_MMD; i += 256) s += bp[i];
    __shared__ float r4[4];
    float w = waveReduce(s);
    if ((t & 63) == 0) r4[t >> 6] = w;
    __syncthreads();
    if (t == 0)
        out[0] = (r4[0] + r4[1] + r4[2] + r4[3]) * (1.f / (4096.f * 4096.f));
}

extern "C" void kernel_launch(void* const* d_in, const int* in_sizes, int n_in,
                              void* d_out, int out_size, void* d_ws, size_t ws_size,
                              hipStream_t stream) {
    const float* src = (const float*)d_in[0];
    const float* tgt = (const float*)d_in[1];

    uint8_t* ws = (uint8_t*)d_ws;
    unsigned char* Tp = (unsigned char*)ws;                    // 4,194,304 B
    size_t off = 4194304;
    float* sq      = (float*)(ws + off); off += 32768;         // 8192 f
    int*   partial = (int*)  (ws + off); off += 128 * 512 * 4; // 256 KB
    float* bp      = (float*)(ws + off); off += 8320;          // >=528 f
    float* c16     = (float*)(ws + off);

    k_rowstats<<<2048, 256, 0, stream>>>(src, tgt, Tp, sq);
    k_colsum  <<<64, 256, 0, stream>>>((const unsigned int*)Tp, partial);
    k_bw      <<<1, 512, 0, stream>>>(partial, sq, c16);
    k_mmd     <<<NBLK_MMD, 256, 0, stream>>>(Tp, sq, c16, bp);
    k_final   <<<1, 256, 0, stream>>>(bp, (float*)d_out);
}